// Round 12
// baseline (267.191 us; speedup 1.0000x reference)
//
#include <hip/hip_runtime.h>
#include <cstdint>

// Problem constants (B,S,D,H) from the reference
#define B_ 64
#define S_ 2048
#define D_ 512
#define H_ 512

using f32x4  = __attribute__((ext_vector_type(4))) float;
using bf16x8 = __attribute__((ext_vector_type(8))) short;
using u32x2  = __attribute__((ext_vector_type(2))) unsigned int;

__device__ __forceinline__ unsigned short f2bf(float f) {
  unsigned u = __float_as_uint(f);
  u += 0x7FFFu + ((u >> 16) & 1u);   // round-to-nearest-even
  return (unsigned short)(u >> 16);
}
// packed f32x2 -> bf16x2 (RTE), hardware op (no builtin on gfx950)
__device__ __forceinline__ unsigned int cvtpk(float lo, float hi) {
  unsigned int r;
  asm("v_cvt_pk_bf16_f32 %0, %1, %2" : "=v"(r) : "v"(lo), "v"(hi));
  return r;
}
// tanh via v_exp_f32: 1 - 2/(exp2(2x*log2e)+1); exact saturation at +-inf
__device__ __forceinline__ float fast_tanh(float x) {
  float t = __builtin_amdgcn_exp2f(x * 2.8853900817779268f);
  return 1.0f - 2.0f * __builtin_amdgcn_rcpf(t + 1.0f);
}

// async global->LDS DMA, 16B/lane; dest = wave-uniform base + lane*16 (linear)
__device__ __forceinline__ void gl_lds16g(const void* g, void* l) {
  __builtin_amdgcn_global_load_lds(
      (const __attribute__((address_space(1))) unsigned int*)g,
      (__attribute__((address_space(3))) unsigned int*)l, 16, 0, 0);
}

__device__ __forceinline__ void barrier_raw() {
  asm volatile("" ::: "memory");
  __builtin_amdgcn_s_barrier();
  asm volatile("" ::: "memory");
}

// ---------------------------------------------------------------------------
// k_prep: blocks [0,128): di[b,h] = hidden[b,:].Wd[h,:] + bd[h]
//         blocks [128,256): We fp32 -> bf16 (32768 chunks of 8)
__global__ void k_prep(const float* __restrict__ hidden, const float* __restrict__ Wd,
                       const float* __restrict__ bd, float* __restrict__ di,
                       const float* __restrict__ We, unsigned short* __restrict__ Web) {
  if (blockIdx.x < 128) {
    int idx = blockIdx.x * 256 + threadIdx.x;   // 32768 total
    int h = idx >> 6;
    int b = idx & 63;
    const f32x4* hp = (const f32x4*)(hidden + (size_t)b * D_);
    const f32x4* wp = (const f32x4*)(Wd + (size_t)h * D_);
    float acc = 0.f;
#pragma unroll 8
    for (int i = 0; i < D_ / 4; ++i) {
      f32x4 x = hp[i], y = wp[i];
      acc += x[0] * y[0] + x[1] * y[1] + x[2] * y[2] + x[3] * y[3];
    }
    di[b * H_ + h] = acc + bd[h];
  } else {
    int i = (blockIdx.x - 128) * 256 + threadIdx.x;   // 32768 chunks
    const f32x4* p = (const f32x4*)(We + (size_t)i * 8);
    f32x4 a = p[0], b = p[1];
    bf16x8 o;
    o[0] = (short)f2bf(a[0]); o[1] = (short)f2bf(a[1]);
    o[2] = (short)f2bf(a[2]); o[3] = (short)f2bf(a[3]);
    o[4] = (short)f2bf(b[0]); o[5] = (short)f2bf(b[1]);
    o[6] = (short)f2bf(b[2]); o[7] = (short)f2bf(b[3]);
    *(bf16x8*)(Web + (size_t)i * 8) = o;
  }
}

// ---------------------------------------------------------------------------
// ei-GEMM: m201 8-phase port. BM=BN=256, BK=64 (2 sub-K of 32), 8 waves
// (2M x 4N), wave tile 128x64, acc[8][4], 132 KB LDS, 1 block/CU.
// A fp32 -> reg-staged (8 f32x4 coalesced) -> cvt_pk -> 8 ds_write_b64
// (single named set, written 4 phases after load). B bf16 via gl_lds DMA
// with source-preswizzle: 4 DMAs/wave/K-tile (2 row-halves x 2 kh-halves)
// [R11 bug: only 2 -> rows 128..255 of B never staged -> NaN].
// K=512 -> 8 K-tiles -> 4 iterations x 8 phases.
// Waits: ONLY lgkmcnt(0)+vmcnt(8) at phase 4/8 ends. Steady-state queue
// there = [B-DMA x4 (next tile), A-load x8 (tile after)] = 12; vmcnt(8)
// retires exactly the 4 B-DMAs; A handled by compiler data-dep waits.
// Per phase: {ds_read subtile; [stage]; barrier; setprio(1) 16 MFMA
// setprio(0); barrier}. LDS rows 64B, slot swizzle phys = s ^ ((row>>1)&3).
__global__ __launch_bounds__(512, 2) void k_ei_gemm(
    const float* __restrict__ A, const unsigned short* __restrict__ Bw,
    const float* __restrict__ be, const float* __restrict__ V,
    const float* __restrict__ di, float* __restrict__ ui2) {
  __shared__ __align__(16) unsigned short ldsA[2][512 * 32];   // [buf][kh*256+row][32]
  __shared__ __align__(16) unsigned short ldsB[2][512 * 32];
  __shared__ float ured[8][128];

  const int bid = blockIdx.x;
  const int swz = (bid & 7) * 128 + (bid >> 3);   // bijective (1024 % 8 == 0)
  const int row0 = (swz >> 1) << 8;               // 512 m-tiles of 256 rows
  const int nt   = swz & 1;
  const int cb   = nt << 8;

  const int t  = threadIdx.x;
  const int l  = t & 63;
  const int w  = t >> 6;           // 8 waves: 2M x 4N
  const int wm = (w >> 2) << 7;    // 0 / 128
  const int wn = (w & 3) << 6;     // 0..192
  const int lr = l & 15;
  const int lg = l >> 4;

  // A global: chunk q: row = q*32 + (t>>4), fp32 cols (t&15)*4 (coalesced)
  const float* gA = A + (size_t)(row0 + (t >> 4)) * D_ + ((t & 15) << 2);
  // A ds_write (per chunk q, b64): kh = lr>>3, logical slot (lr>>1)&3,
  // phys = slot ^ ((row>>1)&3), (row>>1)&3 = (2w + (lg>>1))&3 (q-independent)
  const int khw  = lr >> 3;
  const int physw = ((lr >> 1) & 3) ^ ((2 * w + (lg >> 1)) & 3);
  const int eA = ((khw << 8) + (w << 2) + lg) * 32 + (physw << 3) + ((lr & 1) << 2);
  // B DMA source (slot-preswizzled; dest linear). Same swizzle valid for the
  // +128-row half (128 rows shift (row>>1)&3 by 64 ≡ 0 mod 4).
  const unsigned short* gB = Bw + (size_t)(cb + 16 * w + (l >> 2)) * D_ +
                             (((l & 3) ^ ((l >> 3) & 3)) << 3);
  // fragment read slot offset (bf16 elems)
  const int rs = (lg ^ ((lr >> 1) & 3)) << 3;

  f32x4 a0, a1, a2, a3, a4, a5, a6, a7;   // single A staging set
  bf16x8 af[4], bq[4];

#define LOADA(kt) do { const float* p_ = gA + (kt) * 64;                 \
    a0 = *(const f32x4*)(p_);             a1 = *(const f32x4*)(p_ + 16384);  \
    a2 = *(const f32x4*)(p_ + 2*16384);   a3 = *(const f32x4*)(p_ + 3*16384);\
    a4 = *(const f32x4*)(p_ + 4*16384);   a5 = *(const f32x4*)(p_ + 5*16384);\
    a6 = *(const f32x4*)(p_ + 6*16384);   a7 = *(const f32x4*)(p_ + 7*16384);\
  } while (0)

#define WR1(Q, AV, BF) do { u32x2 p_ = {cvtpk(AV[0], AV[1]), cvtpk(AV[2], AV[3])}; \
    *(u32x2*)&ldsA[BF][eA + (Q) * 1024] = p_; } while (0)
#define WRITEA(BF) do { WR1(0, a0, BF); WR1(1, a1, BF); WR1(2, a2, BF); \
    WR1(3, a3, BF); WR1(4, a4, BF); WR1(5, a5, BF); WR1(6, a6, BF);     \
    WR1(7, a7, BF); } while (0)

// 4 DMAs: (row-half 0/1) x (kh 0/1).  kh0 -> LDS rows 0..255, kh1 -> 256..511
#define DMAB(BF, kt) do {                                                    \
    gl_lds16g(gB + (kt) * 64,                 &ldsB[BF][(16 * w) * 32]);       \
    gl_lds16g(gB + 128 * D_ + (kt) * 64,      &ldsB[BF][(128 + 16 * w) * 32]); \
    gl_lds16g(gB + (kt) * 64 + 32,            &ldsB[BF][(256 + 16 * w) * 32]); \
    gl_lds16g(gB + 128 * D_ + (kt) * 64 + 32, &ldsB[BF][(384 + 16 * w) * 32]); \
  } while (0)

#define READ_BQ(BF, KH) do { _Pragma("unroll") for (int ni = 0; ni < 4; ++ni) \
    bq[ni] = *(const bf16x8*)&ldsB[BF][((KH) * 256 + wn + ni * 16 + lr) * 32 + rs]; } while (0)
#define READ_AF(BF, KH, MH) do { _Pragma("unroll") for (int mi = 0; mi < 4; ++mi) \
    af[mi] = *(const bf16x8*)&ldsA[BF][((KH) * 256 + wm + (MH) * 64 + mi * 16 + lr) * 32 + rs]; } while (0)

#define MFMA16(MH) do {                                                  \
    __builtin_amdgcn_s_setprio(1);                                       \
    _Pragma("unroll") for (int mi = 0; mi < 4; ++mi)                     \
      _Pragma("unroll") for (int ni = 0; ni < 4; ++ni)                   \
        acc[(MH) * 4 + mi][ni] = __builtin_amdgcn_mfma_f32_16x16x32_bf16(\
            af[mi], bq[ni], acc[(MH) * 4 + mi][ni], 0, 0, 0);            \
    __builtin_amdgcn_s_setprio(0);                                       \
  } while (0)

#define VMW8 asm volatile("s_waitcnt lgkmcnt(0)\n\ts_waitcnt vmcnt(8)" ::: "memory")
#define VMW0 asm volatile("s_waitcnt lgkmcnt(0)\n\ts_waitcnt vmcnt(0)" ::: "memory")

  f32x4 acc[8][4];
  const f32x4 z = {0.f, 0.f, 0.f, 0.f};
#pragma unroll
  for (int mi = 0; mi < 8; ++mi)
#pragma unroll
    for (int ni = 0; ni < 4; ++ni) acc[mi][ni] = z;

  // prologue: K-tile 0 -> buf0; A(1) -> regs
  LOADA(0);
  DMAB(0, 0);
  WRITEA(0);          // compiler drains A(0) (vmcnt(4)); B-DMA(0) outstanding
  LOADA(1);
  VMW8;               // retires B-DMA(0)x4 (A(1)'s 8 loads stay in flight)
  barrier_raw();

  // 4 iterations x 8 phases; iteration i: compute K-tiles 2i (buf0), 2i+1 (buf1)
#define ITER(I, LASTQ)                                                        \
  do {                                                                        \
    /* P1: T0 kh0 mh0 + stage(2i+1 -> buf1) + load A(2i+2) */                 \
    READ_BQ(0, 0); READ_AF(0, 0, 0);                                          \
    DMAB(1, 2 * (I) + 1);                                                     \
    WRITEA(1);                                                                \
    if (!(LASTQ)) LOADA(2 * (I) + 2);                                         \
    barrier_raw(); MFMA16(0); barrier_raw();                                  \
    /* P2: T0 kh0 mh1 */                                                      \
    READ_AF(0, 0, 1); barrier_raw(); MFMA16(1); barrier_raw();                \
    /* P3: T0 kh1 mh0 */                                                      \
    READ_BQ(0, 1); READ_AF(0, 1, 0); barrier_raw(); MFMA16(0); barrier_raw(); \
    /* P4: T0 kh1 mh1 + retire B-DMA(2i+1) */                                 \
    READ_AF(0, 1, 1); barrier_raw(); MFMA16(1);                               \
    if (LASTQ) { VMW0; } else { VMW8; }                                       \
    barrier_raw();                                                            \
    /* P5: T1 kh0 mh0 + stage(2i+2 -> buf0) + load A(2i+3) */                 \
    READ_BQ(1, 0); READ_AF(1, 0, 0);                                          \
    if (!(LASTQ)) { DMAB(0, 2 * (I) + 2); WRITEA(0); LOADA(2 * (I) + 3); }    \
    barrier_raw(); MFMA16(0); barrier_raw();                                  \
    /* P6: T1 kh0 mh1 */                                                      \
    READ_AF(1, 0, 1); barrier_raw(); MFMA16(1); barrier_raw();                \
    /* P7: T1 kh1 mh0 */                                                      \
    READ_BQ(1, 1); READ_AF(1, 1, 0); barrier_raw(); MFMA16(0); barrier_raw(); \
    /* P8: T1 kh1 mh1 + retire B-DMA(2i+2) */                                 \
    READ_AF(1, 1, 1); barrier_raw(); MFMA16(1);                               \
    if (LASTQ) { VMW0; } else { VMW8; }                                       \
    barrier_raw();                                                            \
  } while (0)

  ITER(0, 0);
  ITER(1, 0);
  ITER(2, 0);
  ITER(3, 1);
#undef ITER
#undef LOADA
#undef WR1
#undef WRITEA
#undef DMAB
#undef READ_BQ
#undef READ_AF
#undef MFMA16
#undef VMW8
#undef VMW0

  // fused ui partials over this block's 256 columns; atomic-free.
  // C/D layout: col = lr, row = lg*4 + j within each 16x16 frag.
  const int b = row0 >> 11;   // BM=256 divides S=2048 -> block-uniform batch
  float uacc[8][4];
#pragma unroll
  for (int mi = 0; mi < 8; ++mi)
#pragma unroll
    for (int j = 0; j < 4; ++j) uacc[mi][j] = 0.f;

#pragma unroll
  for (int ni = 0; ni < 4; ++ni) {
    const int gc = cb + wn + ni * 16 + lr;
    const float vv = V[gc];
    const float base = di[b * H_ + gc] + be[gc];
#pragma unroll
    for (int mi = 0; mi < 8; ++mi)
#pragma unroll
      for (int j = 0; j < 4; ++j)
        uacc[mi][j] += vv * fast_tanh(base + acc[mi][ni][j]);
  }
  // reduce across the 16 lr-lanes; lanes lr==0 (lg=0..3) hold 4-row sums
#pragma unroll
  for (int mi = 0; mi < 8; ++mi)
#pragma unroll
    for (int j = 0; j < 4; ++j) {
      float s = uacc[mi][j];
      s += __shfl_xor(s, 1);
      s += __shfl_xor(s, 2);
      s += __shfl_xor(s, 4);
      s += __shfl_xor(s, 8);
      if (lr == 0) ured[w][mi * 16 + (lg << 2) + j] = s;
    }
  __syncthreads();
  if (t < 256) {
    const int half = t >> 7, r = t & 127;   // waves half*4..half*4+3 share rows
    ui2[nt * (B_ * S_) + row0 + half * 128 + r] =
        ured[half * 4][r] + ured[half * 4 + 1][r] + ured[half * 4 + 2][r] +
        ured[half * 4 + 3][r];
  }
}

// ---------------------------------------------------------------------------
// softmax over S per batch row: sums the 2 ui partials, applies mask -> -inf.
// Mask dtype (bool-bytes vs int32) detected per block from word high-bytes
// (scan limited to first 128KB so it is in-bounds under both layouts).
__global__ void k_softmax(const float* __restrict__ ui2, const void* __restrict__ mask,
                          float* __restrict__ alpha) {
  __shared__ float red[4];
  __shared__ int sfl;
  const int b = blockIdx.x, t = threadIdx.x;
  const int l = t & 63, w = t >> 6;

  if (t == 0) sfl = 0;
  const unsigned int* mw = (const unsigned int*)mask;
  unsigned det = (mw[b * 512 + t] | mw[b * 512 + 256 + t]) & 0xFFFFFF00u;
  __syncthreads();
  if (det) atomicOr(&sfl, 1);
  __syncthreads();
  const int fl = sfl;   // 1 => byte layout

  float u[8];
#pragma unroll
  for (int i = 0; i < 8; ++i) {
    const int idx = b * S_ + t + i * 256;
    const int msk = fl ? (int)((const unsigned char*)mask)[idx]
                       : ((const int*)mask)[idx];
    const float uv = ui2[idx] + ui2[idx + B_ * S_];
    u[i] = msk ? -__builtin_inff() : uv;
  }

  float mx = u[0];
#pragma unroll
  for (int i = 1; i < 8; ++i) mx = fmaxf(mx, u[i]);
#pragma unroll
  for (int off = 32; off; off >>= 1) mx = fmaxf(mx, __shfl_xor(mx, off));
  if (l == 0) red[w] = mx;
  __syncthreads();
  mx = fmaxf(fmaxf(red[0], red[1]), fmaxf(red[2], red[3]));
  __syncthreads();

  float p[8];
  float s = 0.f;
#pragma unroll
  for (int i = 0; i < 8; ++i) {
    p[i] = __builtin_amdgcn_exp2f((u[i] - mx) * 1.4426950408889634f);
    s += p[i];
  }
#pragma unroll
  for (int off = 32; off; off >>= 1) s += __shfl_xor(s, off);
  if (l == 0) red[w] = s;
  __syncthreads();
  s = red[0] + red[1] + red[2] + red[3];

  const float inv = 1.0f / s;
#pragma unroll
  for (int i = 0; i < 8; ++i) alpha[b * S_ + t + i * 256] = p[i] * inv;
}

// ---------------------------------------------------------------------------
// part[chunk][b][d] = sum over 128 s of alpha * ctx (fp32)
__global__ void k_wsum(const float* __restrict__ ctx, const float* __restrict__ alpha,
                       float* __restrict__ part) {
  __shared__ float red[3][512];
  const int b = blockIdx.x >> 4, chunk = blockIdx.x & 15;
  const int t = threadIdx.x;
  const int h0 = (t & 63) << 3;
  const int sw = t >> 6;
  const int s0 = chunk << 7;

  float acc[8] = {0.f, 0.f, 0.f, 0.f, 0.f, 0.f, 0.f, 0.f};
#pragma unroll 2
  for (int k = 0; k < 32; ++k) {
    const int s = s0 + sw + (k << 2);
    const float a = alpha[b * S_ + s];
    const f32x4* e = (const f32x4*)(ctx + ((size_t)(b * S_ + s)) * D_ + h0);
    f32x4 e0 = e[0], e1 = e[1];
#pragma unroll
    for (int j = 0; j < 4; ++j) acc[j] += a * e0[j];
#pragma unroll
    for (int j = 0; j < 4; ++j) acc[4 + j] += a * e1[j];
  }
  if (sw) {
#pragma unroll
    for (int j = 0; j < 8; ++j) red[sw - 1][h0 + j] = acc[j];
  }
  __syncthreads();
  if (sw == 0) {
#pragma unroll
    for (int j = 0; j < 8; ++j)
      part[((chunk << 6) + b) * 512 + h0 + j] =
          acc[j] + red[0][h0 + j] + red[1][h0 + j] + red[2][h0 + j];
  }
}

// ---------------------------------------------------------------------------
// k_tail: collapse part chunks into LDS wsum, then out1 = wsum.We^T + be
__global__ void k_tail(const float* __restrict__ part, const float* __restrict__ We,
                       const float* __restrict__ be, float* __restrict__ out1) {
  __shared__ float wsum_s[512];
  const int b = blockIdx.x, t = threadIdx.x;

  float s = 0.f;
#pragma unroll
  for (int c = 0; c < 16; ++c) s += part[((c << 6) + b) * 512 + t];
  wsum_s[t] = s;
  __syncthreads();

  const f32x4* wp = (const f32x4*)wsum_s;
  const f32x4* ep = (const f32x4*)(We + (size_t)t * D_);
  float acc = 0.f;
#pragma unroll 8
  for (int i = 0; i < D_ / 4; ++i) {
    f32x4 x = wp[i], y = ep[i];
    acc += x[0] * y[0] + x[1] * y[1] + x[2] * y[2] + x[3] * y[3];
  }
  out1[b * H_ + t] = acc + be[t];
}

// ---------------------------------------------------------------------------
extern "C" void kernel_launch(void* const* d_in, const int* in_sizes, int n_in,
                              void* d_out, int out_size, void* d_ws, size_t ws_size,
                              hipStream_t stream) {
  const float* hidden = (const float*)d_in[0];
  const float* ctx    = (const float*)d_in[1];
  const void*  mask   = d_in[2];
  const float* Wd     = (const float*)d_in[3];
  const float* bd     = (const float*)d_in[4];
  const float* We     = (const float*)d_in[5];
  const float* be     = (const float*)d_in[6];
  const float* V      = (const float*)d_in[7];

  float* out   = (float*)d_out;
  float* alpha = out;               // [B,S]
  float* out1  = out + B_ * S_;     // [B,H]

  // ws layout: ui2/part (2MB region) | di (128KB) | Web (512KB)
  char* ws = (char*)d_ws;
  const size_t off_u2  = 0;
  const size_t off_r3  = off_u2 + 4ull * B_ * S_ * 4;   // +2 MiB
  const size_t off_web = off_r3 + (size_t)B_ * H_ * 4;  // +128 KiB

  float* ui2  = (float*)(ws + off_u2);
  float* part = (float*)(ws + off_u2);
  float* di   = (float*)(ws + off_r3);
  unsigned short* Web = (unsigned short*)(ws + off_web);

  k_prep<<<256, 256, 0, stream>>>(hidden, Wd, bd, di, We, Web);
  k_ei_gemm<<<(B_ * S_ / 256) * 2, 512, 0, stream>>>(ctx, Web, be, V, di, ui2);
  k_softmax<<<B_, 256, 0, stream>>>(ui2, mask, alpha);
  k_wsum<<<B_ * 16, 256, 0, stream>>>(ctx, alpha, part);
  k_tail<<<B_, 512, 0, stream>>>(part, We, be, out1);
}